// Round 1
// baseline (1125.709 us; speedup 1.0000x reference)
//
#include <hip/hip_runtime.h>
#include <hip/hip_bf16.h>

// Shapes (fixed per reference): B=65536, D_IN=256, D_HID=256, SHARE=2, NUM_GATE=6
#define BATCH   65536
#define KDIM    256
#define HDIM    256
#define BH      ((size_t)BATCH * HDIM)
#define TM      32          // batch rows per block

typedef __attribute__((ext_vector_type(8))) short  short8;   // 8 x bf16 (4 VGPRs)
typedef __attribute__((ext_vector_type(4))) float  f32x4;    // MFMA accumulator

__device__ __forceinline__ ushort f2bf(float f) {
    __hip_bfloat16 h = __float2bfloat16(f);
    return *reinterpret_cast<ushort*>(&h);
}

__device__ __forceinline__ float fsig(float x) {
    return 1.0f / (1.0f + __expf(-x));
}
__device__ __forceinline__ float ftanh(float x) {
    return 2.0f / (1.0f + __expf(-2.0f * x)) - 1.0f;
}

// ---- Prep: f32 weights -> bf16 in workspace; combine biases ----------------
// wih: 1536x256, whh: 1024x256, wsh: 512x256. Total f32x4 elements: 196608.
__global__ __launch_bounds__(256) void prep_kernel(
    const float* __restrict__ wih, const float* __restrict__ whh,
    const float* __restrict__ wsh,
    const float* __restrict__ bih, const float* __restrict__ bhh,
    const float* __restrict__ bsh,
    ushort* __restrict__ wih_b, ushort* __restrict__ whh_b,
    ushort* __restrict__ wsh_b, float* __restrict__ cbias)
{
    const int gid = blockIdx.x * 256 + threadIdx.x;   // 0..196607
    const int NIH = 1536 * 256 / 4;                   // 98304
    const int NHH = 1024 * 256 / 4;                   // 65536

    const float* src; ushort* dst; int off;
    if (gid < NIH)            { src = wih; dst = wih_b; off = gid; }
    else if (gid < NIH + NHH) { src = whh; dst = whh_b; off = gid - NIH; }
    else                      { src = wsh; dst = wsh_b; off = gid - NIH - NHH; }

    float4 v = reinterpret_cast<const float4*>(src)[off];
    ushort4 o;
    o.x = f2bf(v.x); o.y = f2bf(v.y); o.z = f2bf(v.z); o.w = f2bf(v.w);
    reinterpret_cast<ushort4*>(dst)[off] = o;

    // combined biases: gates 0..3 -> bih+bhh, gates 4..5 -> bih+bsh
    if (gid < 1536) {
        float b = bih[gid] + (gid < 1024 ? bhh[gid] : bsh[gid - 1024]);
        cbias[gid] = b;
    }
}

// ---- Fused cell kernel -----------------------------------------------------
// Block: 256 threads (4 waves). Rows [row0, row0+32). Wave w owns hidden
// units [w*64, w*64+64), processed as 4 col-tiles of 16 units.
// LDS: x/h/s tiles as bf16, 16B chunks XOR-swizzled: slot = chunk ^ (row&7).
__global__ __launch_bounds__(256) void lstm_kernel(
    const float* __restrict__ x, const float* __restrict__ h,
    const float* __restrict__ cmin, const float* __restrict__ smin,
    const float* __restrict__ mask, const int* __restrict__ idxp,
    const ushort* __restrict__ wih_b, const ushort* __restrict__ whh_b,
    const ushort* __restrict__ wsh_b, const float* __restrict__ cbias,
    float* __restrict__ out)
{
    __shared__ ushort lds[3][TM * KDIM];   // 3 x 16KB = 48KB

    const int tid  = threadIdx.x;
    const int row0 = blockIdx.x * TM;
    const int idx  = idxp[0];
    const float* s = smin + (size_t)idx * BH;

    // ---- stage x, h, s[idx] rows into LDS as bf16 (swizzled 16B chunks) ----
    const float* srcs[3] = { x, h, s };
    #pragma unroll
    for (int si = 0; si < 3; ++si) {
        const float* src = srcs[si] + (size_t)row0 * KDIM;
        short8* dst = reinterpret_cast<short8*>(lds[si]);
        #pragma unroll
        for (int i = 0; i < 4; ++i) {
            int id = i * 256 + tid;          // 0..1023 chunk id
            int m  = id >> 5;                // row 0..31
            int c  = id & 31;                // 16B chunk within row
            int slot = c ^ (m & 7);
            const float4* g = reinterpret_cast<const float4*>(src + m * KDIM + c * 8);
            float4 a = g[0], b = g[1];
            union { short8 v; ushort u[8]; } pk;
            pk.u[0] = f2bf(a.x); pk.u[1] = f2bf(a.y);
            pk.u[2] = f2bf(a.z); pk.u[3] = f2bf(a.w);
            pk.u[4] = f2bf(b.x); pk.u[5] = f2bf(b.y);
            pk.u[6] = f2bf(b.z); pk.u[7] = f2bf(b.w);
            dst[m * 32 + slot] = pk.v;
        }
    }
    __syncthreads();

    const int lane = tid & 63;
    const int wave = tid >> 6;        // 0..3
    const int col  = lane & 15;       // MFMA n / m within tile
    const int q    = lane >> 4;       // quad -> k-slice / D-row group
    const int ub   = wave * 64;

    const short8* ldsx = reinterpret_cast<const short8*>(lds[0]);
    const short8* ldsh = reinterpret_cast<const short8*>(lds[1]);
    const short8* ldss = reinterpret_cast<const short8*>(lds[2]);
    const short8* Wih  = reinterpret_cast<const short8*>(wih_b);
    const short8* Whh  = reinterpret_cast<const short8*>(whh_b);
    const short8* Wsh  = reinterpret_cast<const short8*>(wsh_b);

    for (int ct = 0; ct < 4; ++ct) {
        const int u0 = ub + ct * 16;
        const int wrow = u0 + col;      // unit index this lane loads weights for

        f32x4 accz[2][4];               // i, f, o, c_hat  (x2 row-tiles)
        f32x4 accb[2][2];               // b0, b1
        #pragma unroll
        for (int rt = 0; rt < 2; ++rt) {
            #pragma unroll
            for (int g = 0; g < 4; ++g) accz[rt][g] = (f32x4){0.f,0.f,0.f,0.f};
            #pragma unroll
            for (int g = 0; g < 2; ++g) accb[rt][g] = (f32x4){0.f,0.f,0.f,0.f};
        }

        #pragma unroll
        for (int t = 0; t < 8; ++t) {
            const int c = t * 4 + q;    // 16B chunk index within K=256
            // A fragments from LDS
            short8 ax[2], ah[2], as2[2];
            #pragma unroll
            for (int rt = 0; rt < 2; ++rt) {
                int m = rt * 16 + col;
                int o = m * 32 + (c ^ (m & 7));
                ax[rt] = ldsx[o]; ah[rt] = ldsh[o]; as2[rt] = ldss[o];
            }
            // B fragments (weights) from global/L2: row = gate*256 + unit
            short8 bw[6], bh2[4], bs2[2];
            #pragma unroll
            for (int g = 0; g < 6; ++g) bw[g]  = Wih[(g * 256 + wrow) * 32 + c];
            #pragma unroll
            for (int g = 0; g < 4; ++g) bh2[g] = Whh[(g * 256 + wrow) * 32 + c];
            #pragma unroll
            for (int g = 0; g < 2; ++g) bs2[g] = Wsh[(g * 256 + wrow) * 32 + c];

            #pragma unroll
            for (int rt = 0; rt < 2; ++rt) {
                #pragma unroll
                for (int g = 0; g < 4; ++g) {
                    accz[rt][g] = __builtin_amdgcn_mfma_f32_16x16x32_bf16(
                        ax[rt], bw[g], accz[rt][g], 0, 0, 0);
                    accz[rt][g] = __builtin_amdgcn_mfma_f32_16x16x32_bf16(
                        ah[rt], bh2[g], accz[rt][g], 0, 0, 0);
                }
                #pragma unroll
                for (int g = 0; g < 2; ++g) {
                    accb[rt][g] = __builtin_amdgcn_mfma_f32_16x16x32_bf16(
                        ax[rt], bw[4 + g], accb[rt][g], 0, 0, 0);
                    accb[rt][g] = __builtin_amdgcn_mfma_f32_16x16x32_bf16(
                        as2[rt], bs2[g], accb[rt][g], 0, 0, 0);
                }
            }
        }

        // ---- epilogue: activations + elementwise, direct stores ----
        const int j = u0 + col;
        float cb0 = cbias[0 * 256 + j], cb1 = cbias[1 * 256 + j];
        float cb2 = cbias[2 * 256 + j], cb3 = cbias[3 * 256 + j];
        float cb4 = cbias[4 * 256 + j], cb5 = cbias[5 * 256 + j];

        #pragma unroll
        for (int rt = 0; rt < 2; ++rt) {
            #pragma unroll
            for (int r = 0; r < 4; ++r) {
                const int row = row0 + rt * 16 + q * 4 + r;   // C/D: row = quad*4+reg
                const float mk = mask[row];
                const float cm = cmin[(size_t)row * HDIM + j];
                float zi = accz[rt][0][r] + cb0;
                float zf = accz[rt][1][r] + cb1;
                float zo = accz[rt][2][r] + cb2;
                float zc = accz[rt][3][r] + cb3;
                float z0 = accb[rt][0][r] + cb4;
                float z1 = accb[rt][1][r] + cb5;

                float iv = fsig(zi), fv = fsig(zf), ov = fsig(zo);
                float ctv = (fv * cm + iv * ftanh(zc)) * mk;
                float tc  = ftanh(ctv) * mk;

                const size_t o = (size_t)row * HDIM + j;
                out[o]          = ov * tc;        // h
                out[BH + o]     = ctv;            // c_t
                out[2 * BH + o] = fsig(z0) * tc;  // s[0]
                out[3 * BH + o] = fsig(z1) * tc;  // s[1]
            }
        }
    }
}

extern "C" void kernel_launch(void* const* d_in, const int* in_sizes, int n_in,
                              void* d_out, int out_size, void* d_ws, size_t ws_size,
                              hipStream_t stream) {
    const float* input    = (const float*)d_in[0];
    const float* h_minors = (const float*)d_in[1];
    const float* c_minors = (const float*)d_in[2];
    const float* s_minors = (const float*)d_in[3];
    const float* mask     = (const float*)d_in[4];
    const float* wih      = (const float*)d_in[5];
    const float* whh      = (const float*)d_in[6];
    const float* wsh      = (const float*)d_in[7];
    const float* bih      = (const float*)d_in[8];
    const float* bhh      = (const float*)d_in[9];
    const float* bsh      = (const float*)d_in[10];
    const int*   idx      = (const int*)d_in[11];

    char* ws = (char*)d_ws;
    ushort* wih_b = (ushort*)(ws + 0);          // 1536*256*2 = 786432
    ushort* whh_b = (ushort*)(ws + 786432);     // 1024*256*2 = 524288
    ushort* wsh_b = (ushort*)(ws + 1310720);    //  512*256*2 = 262144
    float*  cbias = (float*)(ws + 1572864);     // 6*256*4    = 6144

    prep_kernel<<<768, 256, 0, stream>>>(wih, whh, wsh, bih, bhh, bsh,
                                         wih_b, whh_b, wsh_b, cbias);
    lstm_kernel<<<BATCH / TM, 256, 0, stream>>>(
        input, h_minors, c_minors, s_minors, mask, idx,
        wih_b, whh_b, wsh_b, cbias, (float*)d_out);
}

// Round 2
// 807.814 us; speedup vs baseline: 1.3935x; 1.3935x over previous
//
#include <hip/hip_runtime.h>
#include <hip/hip_bf16.h>

// Shapes (fixed per reference): B=65536, D_IN=256, D_HID=256, SHARE=2, NUM_GATE=6
#define BATCH   65536
#define KDIM    256
#define HDIM    256
#define BH      ((size_t)BATCH * HDIM)
#define TM      32          // batch rows per block

typedef __attribute__((ext_vector_type(8))) short  short8;   // 8 x bf16 (4 VGPRs)
typedef __attribute__((ext_vector_type(4))) float  f32x4;    // MFMA accumulator

__device__ __forceinline__ ushort f2bf(float f) {
    __hip_bfloat16 h = __float2bfloat16(f);
    return *reinterpret_cast<ushort*>(&h);
}

__device__ __forceinline__ float fsig(float x) {
    return 1.0f / (1.0f + __expf(-x));
}
__device__ __forceinline__ float ftanh(float x) {
    return 2.0f / (1.0f + __expf(-2.0f * x)) - 1.0f;
}

// ---- Prep: f32 weights -> pre-swizzled bf16 fragment stream ----------------
// Output layout: Wpk[tile][t][m][lane], 16B per entry, so the main kernel's
// per-(tile,t,m) weight load is base + lane*16B — one contiguous 1KB segment.
//   tile 0..15 : 16-unit column tile (unit = tile*16 + (lane&15))
//   t    0..7  : K-step (K=32 slice); chunk c = t*4 + (lane>>4)
//   m    0..11 : matrix row-set: 0..5 = ih gates, 6..9 = hh gates, 10..11 = sh
// Total entries: 16*8*12*64 = 98304 (1.5 MB).
__global__ __launch_bounds__(256) void prep_kernel(
    const float* __restrict__ wih, const float* __restrict__ whh,
    const float* __restrict__ wsh,
    const float* __restrict__ bih, const float* __restrict__ bhh,
    const float* __restrict__ bsh,
    ushort* __restrict__ wpk, float* __restrict__ cbias)
{
    const int gid = blockIdx.x * 256 + threadIdx.x;   // 0..98303

    const int lane = gid & 63;
    int rest = gid >> 6;
    const int m    = rest % 12;  rest /= 12;
    const int t    = rest & 7;
    const int tile = rest >> 3;

    const int col  = lane & 15;
    const int q    = lane >> 4;
    const int unit = tile * 16 + col;
    const int c    = t * 4 + q;              // 16B chunk (8 floats) within K=256

    const float* src; int row;
    if (m < 6)       { src = wih; row = m * 256 + unit; }
    else if (m < 10) { src = whh; row = (m - 6) * 256 + unit; }
    else             { src = wsh; row = (m - 10) * 256 + unit; }

    const float4* g = reinterpret_cast<const float4*>(src + row * 256 + c * 8);
    float4 a = g[0], b = g[1];
    union { short8 v; ushort u[8]; } pk;
    pk.u[0] = f2bf(a.x); pk.u[1] = f2bf(a.y);
    pk.u[2] = f2bf(a.z); pk.u[3] = f2bf(a.w);
    pk.u[4] = f2bf(b.x); pk.u[5] = f2bf(b.y);
    pk.u[6] = f2bf(b.z); pk.u[7] = f2bf(b.w);
    reinterpret_cast<short8*>(wpk)[gid] = pk.v;

    // combined biases: gates 0..3 -> bih+bhh, gates 4..5 -> bih+bsh
    if (gid < 1536) {
        float b2 = bih[gid] + (gid < 1024 ? bhh[gid] : bsh[gid - 1024]);
        cbias[gid] = b2;
    }
}

// ---- Fused cell kernel -----------------------------------------------------
// Block: 256 threads (4 waves). Rows [row0, row0+32). Wave w owns hidden
// units [w*64, w*64+64), processed as 4 col-tiles of 16 units.
// LDS: x/h/s tiles as bf16, 16B chunks XOR-swizzled: slot = chunk ^ (row&7).
__global__ __launch_bounds__(256) void lstm_kernel(
    const float* __restrict__ x, const float* __restrict__ h,
    const float* __restrict__ cmin, const float* __restrict__ smin,
    const float* __restrict__ mask, const int* __restrict__ idxp,
    const ushort* __restrict__ wpk, const float* __restrict__ cbias,
    float* __restrict__ out)
{
    __shared__ ushort lds[3][TM * KDIM];   // 3 x 16KB = 48KB

    const int tid  = threadIdx.x;
    const int row0 = blockIdx.x * TM;
    const int idx  = idxp[0];
    const float* s = smin + (size_t)idx * BH;

    // ---- stage x, h, s[idx] rows into LDS as bf16 (swizzled 16B chunks) ----
    const float* srcs[3] = { x, h, s };
    #pragma unroll
    for (int si = 0; si < 3; ++si) {
        const float* src = srcs[si] + (size_t)row0 * KDIM;
        short8* dst = reinterpret_cast<short8*>(lds[si]);
        #pragma unroll
        for (int i = 0; i < 4; ++i) {
            int id = i * 256 + tid;          // 0..1023 chunk id
            int m  = id >> 5;                // row 0..31
            int c  = id & 31;                // 16B chunk within row
            int slot = c ^ (m & 7);
            const float4* g = reinterpret_cast<const float4*>(src + m * KDIM + c * 8);
            float4 a = g[0], b = g[1];
            union { short8 v; ushort u[8]; } pk;
            pk.u[0] = f2bf(a.x); pk.u[1] = f2bf(a.y);
            pk.u[2] = f2bf(a.z); pk.u[3] = f2bf(a.w);
            pk.u[4] = f2bf(b.x); pk.u[5] = f2bf(b.y);
            pk.u[6] = f2bf(b.z); pk.u[7] = f2bf(b.w);
            dst[m * 32 + slot] = pk.v;
        }
    }
    __syncthreads();

    const int lane = tid & 63;
    const int wave = tid >> 6;        // 0..3
    const int col  = lane & 15;       // MFMA n / m within tile
    const int q    = lane >> 4;       // quad -> k-slice / D-row group
    const int ub   = wave * 64;

    const short8* ldsx = reinterpret_cast<const short8*>(lds[0]);
    const short8* ldsh = reinterpret_cast<const short8*>(lds[1]);
    const short8* ldss = reinterpret_cast<const short8*>(lds[2]);
    const short8* Wp0  = reinterpret_cast<const short8*>(wpk);

    for (int ct = 0; ct < 4; ++ct) {
        const int tileIdx = wave * 4 + ct;
        const int u0 = ub + ct * 16;
        // fragment stream for this col-tile: [t][m][lane]
        const short8* Wp = Wp0 + (size_t)tileIdx * (8 * 12 * 64) + lane;

        f32x4 accz[2][4];               // i, f, o, c_hat  (x2 row-tiles)
        f32x4 accb[2][2];               // b0, b1
        #pragma unroll
        for (int rt = 0; rt < 2; ++rt) {
            #pragma unroll
            for (int g = 0; g < 4; ++g) accz[rt][g] = (f32x4){0.f,0.f,0.f,0.f};
            #pragma unroll
            for (int g = 0; g < 2; ++g) accb[rt][g] = (f32x4){0.f,0.f,0.f,0.f};
        }

        #pragma unroll
        for (int t = 0; t < 8; ++t) {
            const int c = t * 4 + q;    // 16B chunk index within K=256
            // A fragments from LDS
            short8 ax[2], ah[2], as2[2];
            #pragma unroll
            for (int rt = 0; rt < 2; ++rt) {
                int m = rt * 16 + col;
                int o = m * 32 + (c ^ (m & 7));
                ax[rt] = ldsx[o]; ah[rt] = ldsh[o]; as2[rt] = ldss[o];
            }
            // B fragments (weights): fully coalesced 1KB loads
            short8 bw[12];
            #pragma unroll
            for (int m = 0; m < 12; ++m) bw[m] = Wp[(t * 12 + m) * 64];

            #pragma unroll
            for (int rt = 0; rt < 2; ++rt) {
                #pragma unroll
                for (int g = 0; g < 4; ++g) {
                    accz[rt][g] = __builtin_amdgcn_mfma_f32_16x16x32_bf16(
                        ax[rt], bw[g], accz[rt][g], 0, 0, 0);
                    accz[rt][g] = __builtin_amdgcn_mfma_f32_16x16x32_bf16(
                        ah[rt], bw[6 + g], accz[rt][g], 0, 0, 0);
                }
                #pragma unroll
                for (int g = 0; g < 2; ++g) {
                    accb[rt][g] = __builtin_amdgcn_mfma_f32_16x16x32_bf16(
                        ax[rt], bw[4 + g], accb[rt][g], 0, 0, 0);
                    accb[rt][g] = __builtin_amdgcn_mfma_f32_16x16x32_bf16(
                        as2[rt], bw[10 + g], accb[rt][g], 0, 0, 0);
                }
            }
        }

        // ---- epilogue: activations + elementwise, direct stores ----
        const int j = u0 + col;
        float cb0 = cbias[0 * 256 + j], cb1 = cbias[1 * 256 + j];
        float cb2 = cbias[2 * 256 + j], cb3 = cbias[3 * 256 + j];
        float cb4 = cbias[4 * 256 + j], cb5 = cbias[5 * 256 + j];

        #pragma unroll
        for (int rt = 0; rt < 2; ++rt) {
            #pragma unroll
            for (int r = 0; r < 4; ++r) {
                const int row = row0 + rt * 16 + q * 4 + r;   // C/D: row = quad*4+reg
                const float mk = mask[row];
                const float cm = cmin[(size_t)row * HDIM + j];
                float zi = accz[rt][0][r] + cb0;
                float zf = accz[rt][1][r] + cb1;
                float zo = accz[rt][2][r] + cb2;
                float zc = accz[rt][3][r] + cb3;
                float z0 = accb[rt][0][r] + cb4;
                float z1 = accb[rt][1][r] + cb5;

                float iv = fsig(zi), fv = fsig(zf), ov = fsig(zo);
                float ctv = (fv * cm + iv * ftanh(zc)) * mk;
                float tc  = ftanh(ctv) * mk;

                const size_t o = (size_t)row * HDIM + j;
                out[o]          = ov * tc;        // h
                out[BH + o]     = ctv;            // c_t
                out[2 * BH + o] = fsig(z0) * tc;  // s[0]
                out[3 * BH + o] = fsig(z1) * tc;  // s[1]
            }
        }
    }
}

extern "C" void kernel_launch(void* const* d_in, const int* in_sizes, int n_in,
                              void* d_out, int out_size, void* d_ws, size_t ws_size,
                              hipStream_t stream) {
    const float* input    = (const float*)d_in[0];
    const float* h_minors = (const float*)d_in[1];
    const float* c_minors = (const float*)d_in[2];
    const float* s_minors = (const float*)d_in[3];
    const float* mask     = (const float*)d_in[4];
    const float* wih      = (const float*)d_in[5];
    const float* whh      = (const float*)d_in[6];
    const float* wsh      = (const float*)d_in[7];
    const float* bih      = (const float*)d_in[8];
    const float* bhh      = (const float*)d_in[9];
    const float* bsh      = (const float*)d_in[10];
    const int*   idx      = (const int*)d_in[11];

    char* ws = (char*)d_ws;
    ushort* wpk  = (ushort*)(ws + 0);           // 98304*16B = 1572864
    float*  cbias = (float*)(ws + 1572864);     // 6*256*4   = 6144

    prep_kernel<<<384, 256, 0, stream>>>(wih, whh, wsh, bih, bhh, bsh,
                                         wpk, cbias);
    lstm_kernel<<<BATCH / TM, 256, 0, stream>>>(
        input, h_minors, c_minors, s_minors, mask, idx,
        wpk, cbias, (float*)d_out);
}